// Round 8
// baseline (316.521 us; speedup 1.0000x reference)
//
#include <hip/hip_runtime.h>

#define D 128
#define N_CLS 40

// ---------------------------------------------------------------------------
// bf16 helpers (RNE)
// ---------------------------------------------------------------------------
__device__ __forceinline__ unsigned f2bf(float f) {
  unsigned u = __builtin_bit_cast(unsigned, f);
  u += 0x7fffu + ((u >> 16) & 1u);
  return u >> 16;
}
__device__ __forceinline__ float bf_lo(unsigned u) {
  return __builtin_bit_cast(float, u << 16);
}
__device__ __forceinline__ float bf_hi(unsigned u) {
  return __builtin_bit_cast(float, u & 0xffff0000u);
}

// ---------------------------------------------------------------------------
// CSR build step 1: counts[dst[e]]++
// ---------------------------------------------------------------------------
__global__ __launch_bounds__(256) void count_kernel(
    const int* __restrict__ dst, int* __restrict__ counts, int n_edges) {
  int e = blockIdx.x * 256 + threadIdx.x;
  if (e < n_edges) atomicAdd(&counts[dst[e]], 1);
}

// 3-phase device-wide exclusive scan over counts[n] (n % 4 == 0).
__global__ __launch_bounds__(256) void scan_partA(
    const int* __restrict__ counts, int* __restrict__ partials, int n4) {
  __shared__ int sh[256];
  const int tid = threadIdx.x;
  const int g = blockIdx.x * 256 + tid;
  int s = 0;
  if (g < n4) {
    const int4 c = reinterpret_cast<const int4*>(counts)[g];
    s = c.x + c.y + c.z + c.w;
  }
  sh[tid] = s;
  __syncthreads();
  for (int off = 128; off > 0; off >>= 1) {
    if (tid < off) sh[tid] += sh[tid + off];
    __syncthreads();
  }
  if (tid == 0) partials[blockIdx.x] = sh[0];
}

__global__ __launch_bounds__(64) void scan_partB(
    int* __restrict__ partials, int* __restrict__ row_start, int nP,
    int n, int n_edges) {
  const int lane = threadIdx.x;
  int v = (lane < nP) ? partials[lane] : 0;
  int x = v;
  for (int off = 1; off < 64; off <<= 1) {
    int y = __shfl_up(x, off, 64);
    if (lane >= off) x += y;
  }
  if (lane < nP) partials[lane] = x - v;
  if (lane == 0) row_start[n] = n_edges;
}

__global__ __launch_bounds__(256) void scan_partC(
    int* __restrict__ counts, const int* __restrict__ partials,
    int* __restrict__ row_start, int n4) {
  __shared__ int sh[256];
  const int tid = threadIdx.x;
  const int g = blockIdx.x * 256 + tid;
  int4 c = make_int4(0, 0, 0, 0);
  if (g < n4) c = reinterpret_cast<const int4*>(counts)[g];
  const int s0 = c.x;
  const int s1 = s0 + c.y;
  const int s2 = s1 + c.z;
  const int s3 = s2 + c.w;
  sh[tid] = s3;
  __syncthreads();
  for (int off = 1; off < 256; off <<= 1) {
    int y = (tid >= off) ? sh[tid - off] : 0;
    __syncthreads();
    sh[tid] += y;
    __syncthreads();
  }
  if (g < n4) {
    const int base = partials[blockIdx.x] + sh[tid] - s3;
    const int4 rs = make_int4(base, base + s0, base + s1, base + s2);
    reinterpret_cast<int4*>(row_start)[g] = rs;
    reinterpret_cast<int4*>(counts)[g] = rs;
  }
}

__global__ __launch_bounds__(256) void fill_kernel(
    const int* __restrict__ src, const int* __restrict__ dst,
    int* __restrict__ cursor, int* __restrict__ col_idx, int n_edges) {
  int e = blockIdx.x * 256 + threadIdx.x;
  if (e < n_edges) {
    int p = atomicAdd(&cursor[dst[e]], 1);
    col_idx[p] = src[e];
  }
}

// ---------------------------------------------------------------------------
// Merged converter: blocks [0, nxb) convert x (float4 -> 2x packed bf16),
// blocks [nxb, ...) convert W0/W1/W2 (W2 padded to 48 rows).
// ---------------------------------------------------------------------------
__global__ __launch_bounds__(256) void convert_all(
    const float4* __restrict__ x4, uint2* __restrict__ xb, int n4, int nxb,
    const float* __restrict__ W0, const float* __restrict__ W1,
    const float* __restrict__ W2, unsigned short* __restrict__ W0b,
    unsigned short* __restrict__ W1b, unsigned short* __restrict__ W2b) {
  if ((int)blockIdx.x < nxb) {
    int i = blockIdx.x * 256 + threadIdx.x;
    if (i < n4) {
      float4 v = x4[i];
      xb[i] = make_uint2(f2bf(v.x) | (f2bf(v.y) << 16),
                         f2bf(v.z) | (f2bf(v.w) << 16));
    }
  } else {
    int idx = (blockIdx.x - nxb) * 256 + threadIdx.x;
    const int n0 = 128 * 128, n1 = 128 * 128, n2 = 48 * 128;
    if (idx < n0) {
      W0b[idx] = (unsigned short)f2bf(W0[idx]);
    } else if (idx < n0 + n1) {
      int i = idx - n0;
      W1b[i] = (unsigned short)f2bf(W1[i]);
    } else if (idx < n0 + n1 + n2) {
      int i = idx - n0 - n1;
      int r = i >> 7;
      W2b[i] = (r < N_CLS) ? (unsigned short)f2bf(W2[i]) : (unsigned short)0;
    }
  }
}

// ---------------------------------------------------------------------------
// Fused gather+GEMM:  out = act( (H + segsum(H[src],dst)) @ B^T + bias )
// Block = 256 thr = 4 independent waves; wave w owns nodes m_base..+15.
// Phase 1 (per wave): for each of its 16 nodes, the FULL wave gathers the
//   256 B row sum (wave-uniform loop bounds; masked 8-wide rounds -> exactly
//   ceil(deg/8) dependent rounds, no divergent tail) and parks it in LDS.
//   LDS row stride 68 dwords: write banks 2-way, frag-read banks 2-way (free).
// Phase 2 (same wave): 16-row MFMA tile straight from LDS; B (=W) from L2.
// C/D: col = lane&15, row = (lane>>4)*4 + reg.
// ---------------------------------------------------------------------------
typedef __attribute__((ext_vector_type(8))) short bf16x8;
typedef __attribute__((ext_vector_type(4))) float f32x4;

template <int NT, bool RELU, bool OUTBF16>
__global__ __launch_bounds__(256) void fused_gg(
    const unsigned* __restrict__ H, const int* __restrict__ row_start,
    const int* __restrict__ col_idx, const unsigned short* __restrict__ B,
    const float* __restrict__ bias, void* __restrict__ out,
    int M, int ncols) {
  __shared__ unsigned lds[4 * 16 * 68];
  const int wv = threadIdx.x >> 6;
  const int lane = threadIdx.x & 63;
  const int m_base = blockIdx.x * 64 + wv * 16;
  unsigned* Lw = lds + wv * (16 * 68);

  // ---- Phase 1: gather 16 rows into LDS ----
  for (int i = 0; i < 16; ++i) {
    const int node = m_base + i;
    float sx = 0.f, sy = 0.f;
    if (node < M) {
      const int s = row_start[node];
      const int e = row_start[node + 1];
      const unsigned su = H[(size_t)node * 64 + lane];  // self term
      float ax[8], ay[8];
      ax[0] = bf_lo(su); ay[0] = bf_hi(su);
#pragma unroll
      for (int k = 1; k < 8; ++k) { ax[k] = 0.f; ay[k] = 0.f; }
      for (int j = s; j < e; j += 8) {
        unsigned v[8];
#pragma unroll
        for (int k = 0; k < 8; ++k) {
          int idx = j + k;
          int u = col_idx[(idx < e) ? idx : (e - 1)];
          unsigned vv = H[(size_t)u * 64 + lane];
          v[k] = (idx < e) ? vv : 0u;
        }
#pragma unroll
        for (int k = 0; k < 8; ++k) { ax[k] += bf_lo(v[k]); ay[k] += bf_hi(v[k]); }
      }
      sx = ((ax[0] + ax[1]) + (ax[2] + ax[3])) + ((ax[4] + ax[5]) + (ax[6] + ax[7]));
      sy = ((ay[0] + ay[1]) + (ay[2] + ay[3])) + ((ay[4] + ay[5]) + (ay[6] + ay[7]));
    }
    Lw[i * 68 + lane] = f2bf(sx) | (f2bf(sy) << 16);
  }
  __syncthreads();

  // ---- Phase 2: MFMA from LDS ----
  const int r16 = lane & 15;
  const int quad = lane >> 4;

  bf16x8 af[4];
#pragma unroll
  for (int ks = 0; ks < 4; ++ks)
    af[ks] = *reinterpret_cast<const bf16x8*>(
        reinterpret_cast<const short*>(Lw + r16 * 68 + ks * 16 + quad * 4));

  f32x4 acc[NT];
#pragma unroll
  for (int nt = 0; nt < NT; ++nt) {
    acc[nt] = (f32x4){0.f, 0.f, 0.f, 0.f};
    const short* Bp = (const short*)B + (size_t)(nt * 16 + r16) * D + quad * 8;
#pragma unroll
    for (int ks = 0; ks < 4; ++ks) {
      bf16x8 bf = *reinterpret_cast<const bf16x8*>(Bp + ks * 32);
      acc[nt] = __builtin_amdgcn_mfma_f32_16x16x32_bf16(af[ks], bf, acc[nt], 0, 0, 0);
    }
  }

  // ---- Epilogue ----
  const int orow = m_base + quad * 4;
#pragma unroll
  for (int nt = 0; nt < NT; ++nt) {
    int col = nt * 16 + r16;
    float bv = (col < ncols) ? bias[col] : 0.f;
#pragma unroll
    for (int r = 0; r < 4; ++r) {
      int grow = orow + r;
      if (grow < M && col < ncols) {
        float v = acc[nt][r] + bv;
        if (RELU) v = fmaxf(v, 0.f);
        if (OUTBF16)
          ((unsigned short*)out)[(size_t)grow * D + col] = (unsigned short)f2bf(v);
        else
          ((float*)out)[(size_t)grow * ncols + col] = v;
      }
    }
  }
}

// ---------------------------------------------------------------------------
extern "C" void kernel_launch(void* const* d_in, const int* in_sizes, int n_in,
                              void* d_out, int out_size, void* d_ws, size_t ws_size,
                              hipStream_t stream) {
  const float* x   = (const float*)d_in[0];
  const int*   src = (const int*)d_in[1];
  const int*   dst = (const int*)d_in[2];
  const float* W0  = (const float*)d_in[3];
  const float* b0  = (const float*)d_in[4];
  const float* W1  = (const float*)d_in[5];
  const float* b1  = (const float*)d_in[6];
  const float* W2  = (const float*)d_in[7];
  const float* b2  = (const float*)d_in[8];
  float* out = (float*)d_out;

  const int M = in_sizes[0] / D;  // 50000
  const int E = in_sizes[1];      // 600000

  // ws layout (16B-aligned chunks):
  // [xb bf16 M*128][h0 bf16 M*128][h1 bf16 M*128][W0b][W1b][W2b 48x128]
  // [counts M][row_start M+4][col_idx E][partials 64]
  char* p = (char*)d_ws;
  unsigned short* xb = (unsigned short*)p;  p += (size_t)M * D * 2;
  unsigned short* h0 = (unsigned short*)p;  p += (size_t)M * D * 2;
  unsigned short* h1 = (unsigned short*)p;  p += (size_t)M * D * 2;
  unsigned short* W0b = (unsigned short*)p;  p += 128 * 128 * 2;
  unsigned short* W1b = (unsigned short*)p;  p += 128 * 128 * 2;
  unsigned short* W2b = (unsigned short*)p;  p += 48 * 128 * 2;
  int* counts    = (int*)p;  p += (size_t)M * 4;
  int* row_start = (int*)p;  p += (size_t)(M + 4) * 4;
  int* col_idx   = (int*)p;  p += (size_t)E * 4;
  int* partials  = (int*)p;

  const int n4 = M / 4;
  const int scanBlocks = (n4 + 255) / 256;
  const int edgeBlocks = (E + 255) / 256;
  const int fusedBlocks = (M + 63) / 64;

  const int xConv4 = M * D / 4;
  const int nxb = (xConv4 + 255) / 256;
  const int nwb = (128 * 128 * 2 + 48 * 128 + 255) / 256;

  // --- CSR build ---
  hipMemsetAsync(counts, 0, (size_t)M * sizeof(int), stream);
  count_kernel<<<edgeBlocks, 256, 0, stream>>>(dst, counts, E);
  scan_partA<<<scanBlocks, 256, 0, stream>>>(counts, partials, n4);
  scan_partB<<<1, 64, 0, stream>>>(partials, row_start, scanBlocks, M, E);
  scan_partC<<<scanBlocks, 256, 0, stream>>>(counts, partials, row_start, n4);
  fill_kernel<<<edgeBlocks, 256, 0, stream>>>(src, dst, counts, col_idx, E);

  // --- Convert x + weights to bf16 ---
  convert_all<<<nxb + nwb, 256, 0, stream>>>(
      (const float4*)x, (uint2*)xb, xConv4, nxb, W0, W1, W2, W0b, W1b, W2b);

  // --- Fused layers ---
  fused_gg<8, true, true><<<fusedBlocks, 256, 0, stream>>>(
      (const unsigned*)xb, row_start, col_idx, W0b, b0, h0, M, D);
  fused_gg<8, true, true><<<fusedBlocks, 256, 0, stream>>>(
      (const unsigned*)h0, row_start, col_idx, W1b, b1, h1, M, D);
  fused_gg<3, false, false><<<fusedBlocks, 256, 0, stream>>>(
      (const unsigned*)h1, row_start, col_idx, W2b, b2, out, M, N_CLS);
}

// Round 9
// 294.070 us; speedup vs baseline: 1.0763x; 1.0763x over previous
//
#include <hip/hip_runtime.h>

#define D 128
#define N_CLS 40

// ---------------------------------------------------------------------------
// bf16 helpers (RNE)
// ---------------------------------------------------------------------------
__device__ __forceinline__ unsigned f2bf(float f) {
  unsigned u = __builtin_bit_cast(unsigned, f);
  u += 0x7fffu + ((u >> 16) & 1u);
  return u >> 16;
}
__device__ __forceinline__ float bf_lo(unsigned u) {
  return __builtin_bit_cast(float, u << 16);
}
__device__ __forceinline__ float bf_hi(unsigned u) {
  return __builtin_bit_cast(float, u & 0xffff0000u);
}

// 3-phase device-wide exclusive scan over counts[n] (n % 4 == 0).
__global__ __launch_bounds__(256) void scan_partA(
    const int* __restrict__ counts, int* __restrict__ partials, int n4) {
  __shared__ int sh[256];
  const int tid = threadIdx.x;
  const int g = blockIdx.x * 256 + tid;
  int s = 0;
  if (g < n4) {
    const int4 c = reinterpret_cast<const int4*>(counts)[g];
    s = c.x + c.y + c.z + c.w;
  }
  sh[tid] = s;
  __syncthreads();
  for (int off = 128; off > 0; off >>= 1) {
    if (tid < off) sh[tid] += sh[tid + off];
    __syncthreads();
  }
  if (tid == 0) partials[blockIdx.x] = sh[0];
}

__global__ __launch_bounds__(64) void scan_partB(
    int* __restrict__ partials, int* __restrict__ row_start, int nP,
    int n, int n_edges) {
  const int lane = threadIdx.x;
  int v = (lane < nP) ? partials[lane] : 0;
  int x = v;
  for (int off = 1; off < 64; off <<= 1) {
    int y = __shfl_up(x, off, 64);
    if (lane >= off) x += y;
  }
  if (lane < nP) partials[lane] = x - v;
  if (lane == 0) row_start[n] = n_edges;
}

__global__ __launch_bounds__(256) void scan_partC(
    int* __restrict__ counts, const int* __restrict__ partials,
    int* __restrict__ row_start, int n4) {
  __shared__ int sh[256];
  const int tid = threadIdx.x;
  const int g = blockIdx.x * 256 + tid;
  int4 c = make_int4(0, 0, 0, 0);
  if (g < n4) c = reinterpret_cast<const int4*>(counts)[g];
  const int s0 = c.x;
  const int s1 = s0 + c.y;
  const int s2 = s1 + c.z;
  const int s3 = s2 + c.w;
  sh[tid] = s3;
  __syncthreads();
  for (int off = 1; off < 256; off <<= 1) {
    int y = (tid >= off) ? sh[tid - off] : 0;
    __syncthreads();
    sh[tid] += y;
    __syncthreads();
  }
  if (g < n4) {
    const int base = partials[blockIdx.x] + sh[tid] - s3;
    const int4 rs = make_int4(base, base + s0, base + s1, base + s2);
    reinterpret_cast<int4*>(row_start)[g] = rs;
    reinterpret_cast<int4*>(counts)[g] = rs;
  }
}

__global__ __launch_bounds__(256) void fill_kernel(
    const int* __restrict__ src, const int* __restrict__ dst,
    int* __restrict__ cursor, int* __restrict__ col_idx, int n_edges) {
  int e = blockIdx.x * 256 + threadIdx.x;
  if (e < n_edges) {
    int p = atomicAdd(&cursor[dst[e]], 1);
    col_idx[p] = src[e];
  }
}

// ---------------------------------------------------------------------------
// Merged converter + degree count:
//   blocks [0, nxb):          x float4 -> packed bf16
//   blocks [nxb, nxb+nwb):    W0/W1/W2 -> bf16 (W2 padded to 48 rows)
//   blocks [nxb+nwb, ...):    counts[dst[e]]++  (edge histogram)
// ---------------------------------------------------------------------------
__global__ __launch_bounds__(256) void convert_count(
    const float4* __restrict__ x4, uint2* __restrict__ xb, int n4, int nxb,
    const float* __restrict__ W0, const float* __restrict__ W1,
    const float* __restrict__ W2, unsigned short* __restrict__ W0b,
    unsigned short* __restrict__ W1b, unsigned short* __restrict__ W2b,
    int nwb, const int* __restrict__ dst, int* __restrict__ counts,
    int n_edges) {
  if ((int)blockIdx.x < nxb) {
    int i = blockIdx.x * 256 + threadIdx.x;
    if (i < n4) {
      float4 v = x4[i];
      xb[i] = make_uint2(f2bf(v.x) | (f2bf(v.y) << 16),
                         f2bf(v.z) | (f2bf(v.w) << 16));
    }
  } else if ((int)blockIdx.x < nxb + nwb) {
    int idx = (blockIdx.x - nxb) * 256 + threadIdx.x;
    const int n0 = 128 * 128, n1 = 128 * 128, n2 = 48 * 128;
    if (idx < n0) {
      W0b[idx] = (unsigned short)f2bf(W0[idx]);
    } else if (idx < n0 + n1) {
      int i = idx - n0;
      W1b[i] = (unsigned short)f2bf(W1[i]);
    } else if (idx < n0 + n1 + n2) {
      int i = idx - n0 - n1;
      int r = i >> 7;
      W2b[i] = (r < N_CLS) ? (unsigned short)f2bf(W2[i]) : (unsigned short)0;
    }
  } else {
    int e = (blockIdx.x - nxb - nwb) * 256 + threadIdx.x;
    if (e < n_edges) atomicAdd(&counts[dst[e]], 1);
  }
}

// ---------------------------------------------------------------------------
// Gather-aggregate in bf16: out[n] = h[n] + sum_{j in row n} h[col_idx[j]]
// One wave per node (wave-uniform loop bounds). 1 dword (2 bf16) per lane =
// 256 B/row per load instruction. Masked full-width rounds: exactly
// ceil(deg/8) dependent 8-wide rounds, no serial tail. fp32 accumulation.
// ---------------------------------------------------------------------------
__global__ __launch_bounds__(256) void gather_bf16(
    const unsigned* __restrict__ h, const int* __restrict__ row_start,
    const int* __restrict__ col_idx, unsigned* __restrict__ out, int n_nodes) {
  int wave = (blockIdx.x * 256 + threadIdx.x) >> 6;
  int lane = threadIdx.x & 63;
  if (wave >= n_nodes) return;
  int s = row_start[wave];
  int e = row_start[wave + 1];
  unsigned su = h[(size_t)wave * 64 + lane];  // self term
  float ax[8], ay[8];
  ax[0] = bf_lo(su); ay[0] = bf_hi(su);
#pragma unroll
  for (int i = 1; i < 8; ++i) { ax[i] = 0.f; ay[i] = 0.f; }

  for (int j = s; j < e; j += 8) {
    unsigned v[8];
#pragma unroll
    for (int k = 0; k < 8; ++k) {
      int idx = j + k;
      int u = col_idx[(idx < e) ? idx : (e - 1)];
      unsigned vv = h[(size_t)u * 64 + lane];
      v[k] = (idx < e) ? vv : 0u;
    }
#pragma unroll
    for (int k = 0; k < 8; ++k) { ax[k] += bf_lo(v[k]); ay[k] += bf_hi(v[k]); }
  }

  float sx = (ax[0] + ax[1]) + (ax[2] + ax[3]) + ((ax[4] + ax[5]) + (ax[6] + ax[7]));
  float sy = (ay[0] + ay[1]) + (ay[2] + ay[3]) + ((ay[4] + ay[5]) + (ay[6] + ay[7]));
  out[(size_t)wave * 64 + lane] = f2bf(sx) | (f2bf(sy) << 16);
}

// ---------------------------------------------------------------------------
// MFMA GEMM: out[M, ncols] = act(A[M,128] @ B[NT*16,128]^T + bias)
// A, B bf16 row-major (K=128 contiguous). Block = 256 thr = 4 waves, 64 rows.
// A/B-frag: lane holds row (lane&15), k = (lane>>4)*8 + j  (16 B loads).
// C/D: col = lane&15, row = (lane>>4)*4 + reg.
// ---------------------------------------------------------------------------
typedef __attribute__((ext_vector_type(8))) short bf16x8;
typedef __attribute__((ext_vector_type(4))) float f32x4;

template <int NT, bool RELU, bool OUTBF16>
__global__ __launch_bounds__(256) void gemm_mfma(
    const unsigned short* __restrict__ A, const unsigned short* __restrict__ B,
    const float* __restrict__ bias, void* __restrict__ out, int M, int ncols) {
  const int tid = threadIdx.x;
  const int wv = tid >> 6;
  const int lane = tid & 63;
  const int m_base = blockIdx.x * 64 + wv * 16;
  const int r16 = lane & 15;
  const int quad = lane >> 4;

  const short* Ap = (const short*)A + (size_t)(m_base + r16) * D + quad * 8;
  bf16x8 af[4];
#pragma unroll
  for (int ks = 0; ks < 4; ++ks)
    af[ks] = *reinterpret_cast<const bf16x8*>(Ap + ks * 32);

  f32x4 acc[NT];
#pragma unroll
  for (int nt = 0; nt < NT; ++nt) {
    acc[nt] = (f32x4){0.f, 0.f, 0.f, 0.f};
    const short* Bp = (const short*)B + (size_t)(nt * 16 + r16) * D + quad * 8;
#pragma unroll
    for (int ks = 0; ks < 4; ++ks) {
      bf16x8 bf = *reinterpret_cast<const bf16x8*>(Bp + ks * 32);
      acc[nt] = __builtin_amdgcn_mfma_f32_16x16x32_bf16(af[ks], bf, acc[nt], 0, 0, 0);
    }
  }

  const int orow = m_base + quad * 4;
#pragma unroll
  for (int nt = 0; nt < NT; ++nt) {
    int col = nt * 16 + r16;
    float bv = (col < ncols) ? bias[col] : 0.f;
#pragma unroll
    for (int r = 0; r < 4; ++r) {
      int grow = orow + r;
      if (grow < M && col < ncols) {
        float v = acc[nt][r] + bv;
        if (RELU) v = fmaxf(v, 0.f);
        if (OUTBF16)
          ((unsigned short*)out)[(size_t)grow * D + col] = (unsigned short)f2bf(v);
        else
          ((float*)out)[(size_t)grow * ncols + col] = v;
      }
    }
  }
}

// ---------------------------------------------------------------------------
extern "C" void kernel_launch(void* const* d_in, const int* in_sizes, int n_in,
                              void* d_out, int out_size, void* d_ws, size_t ws_size,
                              hipStream_t stream) {
  const float* x   = (const float*)d_in[0];
  const int*   src = (const int*)d_in[1];
  const int*   dst = (const int*)d_in[2];
  const float* W0  = (const float*)d_in[3];
  const float* b0  = (const float*)d_in[4];
  const float* W1  = (const float*)d_in[5];
  const float* b1  = (const float*)d_in[6];
  const float* W2  = (const float*)d_in[7];
  const float* b2  = (const float*)d_in[8];
  float* out = (float*)d_out;

  const int M = in_sizes[0] / D;  // 50000
  const int E = in_sizes[1];      // 600000

  // ws layout (16B-aligned chunks):
  // [xb bf16 M*128][t bf16 M*128][hb bf16 M*128][W0b][W1b][W2b 48x128]
  // [counts M][row_start M+4][col_idx E][partials 64]
  char* p = (char*)d_ws;
  unsigned short* xb = (unsigned short*)p;  p += (size_t)M * D * 2;
  unsigned short* t  = (unsigned short*)p;  p += (size_t)M * D * 2;
  unsigned short* hb = (unsigned short*)p;  p += (size_t)M * D * 2;
  unsigned short* W0b = (unsigned short*)p;  p += 128 * 128 * 2;
  unsigned short* W1b = (unsigned short*)p;  p += 128 * 128 * 2;
  unsigned short* W2b = (unsigned short*)p;  p += 48 * 128 * 2;
  int* counts    = (int*)p;  p += (size_t)M * 4;
  int* row_start = (int*)p;  p += (size_t)(M + 4) * 4;
  int* col_idx   = (int*)p;  p += (size_t)E * 4;
  int* partials  = (int*)p;

  const int n4 = M / 4;
  const int scanBlocks = (n4 + 255) / 256;
  const int edgeBlocks = (E + 255) / 256;
  const int gatherBlocks = (M * 64 + 255) / 256;  // 1 wave per node
  const int gemmBlocks = (M + 63) / 64;

  const int xConv4 = M * D / 4;
  const int nxb = (xConv4 + 255) / 256;
  const int nwb = (128 * 128 * 2 + 48 * 128 + 255) / 256;

  // --- Zero degree histogram, then fused convert+count ---
  hipMemsetAsync(counts, 0, (size_t)M * sizeof(int), stream);
  convert_count<<<nxb + nwb + edgeBlocks, 256, 0, stream>>>(
      (const float4*)x, (uint2*)xb, xConv4, nxb, W0, W1, W2, W0b, W1b, W2b,
      nwb, dst, counts, E);

  // --- CSR scan + fill ---
  scan_partA<<<scanBlocks, 256, 0, stream>>>(counts, partials, n4);
  scan_partB<<<1, 64, 0, stream>>>(partials, row_start, scanBlocks, M, E);
  scan_partC<<<scanBlocks, 256, 0, stream>>>(counts, partials, row_start, n4);
  fill_kernel<<<edgeBlocks, 256, 0, stream>>>(src, dst, counts, col_idx, E);

  // --- Layer 0 ---
  gather_bf16<<<gatherBlocks, 256, 0, stream>>>(
      (const unsigned*)xb, row_start, col_idx, (unsigned*)t, M);
  gemm_mfma<8, true, true><<<gemmBlocks, 256, 0, stream>>>(t, W0b, b0, hb, M, D);
  // --- Layer 1 ---
  gather_bf16<<<gatherBlocks, 256, 0, stream>>>(
      (const unsigned*)hb, row_start, col_idx, (unsigned*)t, M);
  gemm_mfma<8, true, true><<<gemmBlocks, 256, 0, stream>>>(t, W1b, b1, hb, M, D);
  // --- Layer 2 (fp32 out, no relu) ---
  gather_bf16<<<gatherBlocks, 256, 0, stream>>>(
      (const unsigned*)hb, row_start, col_idx, (unsigned*)t, M);
  gemm_mfma<3, false, false><<<gemmBlocks, 256, 0, stream>>>(t, W2b, b2, out, M, N_CLS);
}